// Round 1
// baseline (703.257 us; speedup 1.0000x reference)
//
#include <hip/hip_runtime.h>
#include <hip/hip_bf16.h>

#define BIGV 1.0e9f
static constexpr int B_  = 32;
static constexpr int L_  = 1024;
static constexpr int F_  = 128;
static constexpr int T_  = 64;
static constexpr int G_  = 16;    // L_/T_
static constexpr int RS_ = 1040;  // padded stride for boundary stores
static constexpr int LDA_ = 136;  // bf16 LDS row stride (128 + 8 pad)

// workspace layout (float offsets)
static constexpr size_t OFF_N1  = 0;
static constexpr size_t OFF_N2  = (size_t)B_ * L_;
static constexpr size_t OFF_ROW = OFF_N2 + (size_t)B_ * L_;
static constexpr size_t SZ_ST   = (size_t)B_ * (G_ + 1) * RS_;
static constexpr size_t OFF_COL = OFF_ROW + SZ_ST;

typedef __attribute__((ext_vector_type(8))) short short8;
typedef __attribute__((ext_vector_type(4))) float f32x4;

__device__ __forceinline__ unsigned pack2(float x, float y) {
  union { float f; unsigned u; } a, b;
  a.f = x; b.f = y;
  unsigned lo = (a.u + 0x7FFFu + ((a.u >> 16) & 1u)) >> 16;
  unsigned hi = (b.u + 0x7FFFu + ((b.u >> 16) & 1u)) >> 16;
  return lo | (hi << 16);
}

// one wave per row of 128 floats; ws[wid] = sum of squares
__global__ void norm_kernel(const float* __restrict__ s1, const float* __restrict__ s2,
                            float* __restrict__ ws) {
  int gt   = blockIdx.x * blockDim.x + threadIdx.x;
  int wid  = gt >> 6;
  int lane = gt & 63;
  const float* src = (wid < B_ * L_) ? (s1 + (size_t)wid * F_)
                                     : (s2 + (size_t)(wid - B_ * L_) * F_);
  float2 v = ((const float2*)src)[lane];
  float s = v.x * v.x + v.y * v.y;
#pragma unroll
  for (int o = 32; o > 0; o >>= 1) s += __shfl_xor(s, o, 64);
  if (lane == 0) ws[wid] = s;
}

__global__ void init_kernel(float* __restrict__ ws) {
  int t = blockIdx.x * blockDim.x + threadIdx.x;
  if (t >= B_ * (L_ + 1)) return;
  int b = t / (L_ + 1);
  int j = t % (L_ + 1);
  float* rowS = ws + OFF_ROW + (size_t)b * (G_ + 1) * RS_;
  float* colS = ws + OFF_COL + (size_t)b * (G_ + 1) * RS_;
  rowS[j] = (j == 0) ? 0.0f : BIGV;  // D[0][j]
  colS[j] = BIGV;                    // D[i][0]
  if (j >= 1 && j <= G_) rowS[(size_t)j * RS_] = BIGV;  // D[r*T][0] corners
}

__global__ __launch_bounds__(64) void tile_kernel(const float* __restrict__ s1,
                                                  const float* __restrict__ s2,
                                                  float* __restrict__ ws, int d) {
  __shared__ short aLds[T_][LDA_];
  __shared__ short bLds[T_][LDA_];
  __shared__ float cLds[T_][T_];   // stride 64 on purpose: diagonal access -> 2-way (free)
  __shared__ float sq1Lds[T_], sq2Lds[T_], rowLds[T_ + 1];

  const int lane = threadIdx.x;
  const int b    = blockIdx.y;
  const int ti   = max(0, d - (G_ - 1)) + blockIdx.x;
  const int tj   = d - ti;

  const float* Ap = s1 + (size_t)b * L_ * F_ + (size_t)ti * T_ * F_;
  const float* Bp = s2 + (size_t)b * L_ * F_ + (size_t)tj * T_ * F_;

  // stage 64x128 fp32 panels -> bf16 LDS
#pragma unroll 4
  for (int it = 0; it < 32; ++it) {
    int idx = it * 256 + lane * 4;
    int r = idx >> 7, cc = idx & 127;
    float4 va = *(const float4*)(Ap + idx);
    float4 vb = *(const float4*)(Bp + idx);
    *(uint2*)&aLds[r][cc] = make_uint2(pack2(va.x, va.y), pack2(va.z, va.w));
    *(uint2*)&bLds[r][cc] = make_uint2(pack2(vb.x, vb.y), pack2(vb.z, vb.w));
  }

  float* rowS = ws + OFF_ROW + (size_t)b * (G_ + 1) * RS_;
  float* colS = ws + OFF_COL + (size_t)b * (G_ + 1) * RS_;
  sq1Lds[lane] = ws[OFF_N1 + (size_t)b * L_ + ti * T_ + lane];
  sq2Lds[lane] = ws[OFF_N2 + (size_t)b * L_ + tj * T_ + lane];
  rowLds[lane] = rowS[(size_t)ti * RS_ + tj * T_ + lane];
  if (lane == 0) rowLds[T_] = rowS[(size_t)ti * RS_ + tj * T_ + T_];
  float colL = colS[(size_t)tj * RS_ + ti * T_ + 1 + lane];
  __syncthreads();

  // 64x64x128 GEMM: dot[a][c] = <s1 row, s2 row>
  f32x4 acc[4][4] = {};
  const int quad = lane >> 4, l16 = lane & 15;
#pragma unroll
  for (int kc = 0; kc < 4; ++kc) {
    short8 af[4], bf[4];
#pragma unroll
    for (int mi = 0; mi < 4; ++mi)
      af[mi] = *(const short8*)&aLds[mi * 16 + l16][kc * 32 + quad * 8];
#pragma unroll
    for (int nj = 0; nj < 4; ++nj)
      bf[nj] = *(const short8*)&bLds[nj * 16 + l16][kc * 32 + quad * 8];
#pragma unroll
    for (int mi = 0; mi < 4; ++mi)
#pragma unroll
      for (int nj = 0; nj < 4; ++nj)
        acc[mi][nj] = __builtin_amdgcn_mfma_f32_16x16x32_bf16(af[mi], bf[nj], acc[mi][nj], 0, 0, 0);
  }

  // epilogue: cost = sqrt(max(sq1+sq2-2dot,0)); C/D layout col=lane&15,row=quad*4+reg
#pragma unroll
  for (int mi = 0; mi < 4; ++mi)
#pragma unroll
    for (int nj = 0; nj < 4; ++nj)
#pragma unroll
      for (int r = 0; r < 4; ++r) {
        int a = mi * 16 + quad * 4 + r;
        int c = nj * 16 + l16;
        float d2 = sq1Lds[a] + sq2Lds[c] - 2.0f * acc[mi][nj][r];
        cLds[a][c] = sqrtf(fmaxf(d2, 0.0f));
      }
  __syncthreads();

  // in-tile wavefront: lane a owns row a; 127 anti-diagonal steps
  const float* Crow = &cLds[lane][0];
  float v1 = BIGV, v2 = BIGV;
  float colDiag = __shfl_up(colL, 1, 64);
  if (lane == 0) colDiag = rowLds[0];

  auto cclamp = [&](int k) { int c = k - lane; return (c < 0) ? 0 : (c > 63 ? 63 : c); };
  float cb0 = Crow[cclamp(0)], cb1 = Crow[cclamp(1)], cb2 = Crow[cclamp(2)], cb3 = Crow[cclamp(3)];
  float bD0 = rowLds[0], bD1 = rowLds[1], bD2 = rowLds[2], bD3 = rowLds[3];
  float bU0 = rowLds[1], bU1 = rowLds[2], bU2 = rowLds[3], bU3 = rowLds[4];

  float* rowOut = rowS + (size_t)(ti + 1) * RS_ + tj * T_ + 1;
  float* colOut = colS + (size_t)(tj + 1) * RS_ + ti * T_ + 1;

#pragma unroll 4
  for (int k = 0; k < 127; ++k) {
    int c = k - lane;
    float sup   = __shfl_up(v1, 1, 64);
    float sdiag = __shfl_up(v2, 1, 64);
    if (lane == 0) { sup = bU0; sdiag = bD0; }
    if (c == 0) sdiag = colDiag;
    float left = (c == 0) ? colL : v1;
    float cur  = cb0 + fminf(sdiag, fminf(sup, left));
    bool act = ((unsigned)c <= 63u);
    if (act) { v2 = v1; v1 = cur; }
    if (c == 63) colOut[lane] = cur;
    if (lane == 63 && act) rowOut[c] = cur;
    // rolling prefetch (depth 4) keeps LDS latency off the serial chain
    cb0 = cb1; cb1 = cb2; cb2 = cb3; cb3 = Crow[cclamp(k + 4)];
    int i4 = k + 4; if (i4 > 64) i4 = 64;
    int i5 = k + 5; if (i5 > 64) i5 = 64;
    bD0 = bD1; bD1 = bD2; bD2 = bD3; bD3 = rowLds[i4];
    bU0 = bU1; bU1 = bU2; bU2 = bU3; bU3 = rowLds[i5];
  }
}

__global__ void final_kernel(const float* __restrict__ ws, const float* __restrict__ sw,
                             float* __restrict__ out) {
  int b = threadIdx.x;
  if (b < B_) {
    float dtw = ws[OFF_ROW + (size_t)b * (G_ + 1) * RS_ + (size_t)G_ * RS_ + L_];
    out[b] = 1.0f / (1.0f + dtw / (float)(L_ + L_));  // softmax of 1-elem vector == 1
  }
  (void)sw;
}

extern "C" void kernel_launch(void* const* d_in, const int* in_sizes, int n_in,
                              void* d_out, int out_size, void* d_ws, size_t ws_size,
                              hipStream_t stream) {
  const float* s1 = (const float*)d_in[0];
  const float* s2 = (const float*)d_in[1];
  const float* sw = (const float*)d_in[2];
  float* out = (float*)d_out;
  float* ws  = (float*)d_ws;

  // norms: one wave per row, 2*B*L rows
  norm_kernel<<<dim3((2 * B_ * L_) / 4), 256, 0, stream>>>(s1, s2, ws);
  init_kernel<<<dim3((B_ * (L_ + 1) + 255) / 256), 256, 0, stream>>>(ws);

  for (int d = 0; d < 2 * G_ - 1; ++d) {
    int lo = max(0, d - (G_ - 1));
    int hi = min(G_ - 1, d);
    int cnt = hi - lo + 1;
    tile_kernel<<<dim3(cnt, B_), 64, 0, stream>>>(s1, s2, ws, d);
  }
  final_kernel<<<1, 64, 0, stream>>>(ws, sw, out);
}

// Round 2
// 272.537 us; speedup vs baseline: 2.5804x; 2.5804x over previous
//
#include <hip/hip_runtime.h>
#include <hip/hip_bf16.h>

#define BIGV 1.0e9f

static constexpr int B_ = 32;
static constexpr int L_ = 1024;
static constexpr int F_ = 128;
static constexpr int SKEW_U = 1160;                       // 1150 used + slack
static constexpr size_t SKEW_PB = (size_t)SKEW_U * 1024;  // floats per batch
static constexpr size_t OFF_N1 = (size_t)B_ * SKEW_PB;    // s1 row norms
static constexpr size_t OFF_N2 = OFF_N1 + (size_t)B_ * L_;
static constexpr int PF_ = 8;        // prefetch depth (steps)
static constexpr int TSTEPS_ = 1152; // 1024 + 2*63 rounded up to x8

typedef __attribute__((ext_vector_type(8))) short short8;
typedef __attribute__((ext_vector_type(4))) float f32x4;

__device__ __forceinline__ unsigned pack2(float x, float y) {
  union { float f; unsigned u; } a, b;
  a.f = x; b.f = y;
  unsigned lo = (a.u + 0x7FFFu + ((a.u >> 16) & 1u)) >> 16;
  unsigned hi = (b.u + 0x7FFFu + ((b.u >> 16) & 1u)) >> 16;
  return lo | (hi << 16);
}

// one wave per row of 128 floats; ws[OFF_N1 + wid] = sum of squares
__global__ void norm_kernel(const float* __restrict__ s1, const float* __restrict__ s2,
                            float* __restrict__ ws) {
  int gt   = blockIdx.x * blockDim.x + threadIdx.x;
  int wid  = gt >> 6;
  int lane = gt & 63;
  const float* src = (wid < B_ * L_) ? (s1 + (size_t)wid * F_)
                                     : (s2 + (size_t)(wid - B_ * L_) * F_);
  float2 v = ((const float2*)src)[lane];
  float s = v.x * v.x + v.y * v.y;
#pragma unroll
  for (int o = 32; o > 0; o >>= 1) s += __shfl_xor(s, o, 64);
  if (lane == 0) ws[OFF_N1 + wid] = s;
}

// cost matrix: C(c,r) = ||s1[r] - s2[c]||, stored skewed:
//   flat = (c + 2*(r>>4))*1024 + r   (per batch), so the dtw wave reads 4KB rows.
__global__ __launch_bounds__(256) void cost_kernel(const float* __restrict__ s1,
                                                   const float* __restrict__ s2,
                                                   float* __restrict__ ws) {
  __shared__ short aL[128][136];  // s1 panel (A operand, m-dim = r)
  __shared__ short bL[128][136];  // s2 panel (B operand, n-dim = c)
  __shared__ float q1[128], q2[128];

  const int tid = threadIdx.x;
  const int b   = blockIdx.y;
  const int tc  = blockIdx.x & 7;   // c tile (s2 rows)
  const int tr  = blockIdx.x >> 3;  // r tile (s1 rows)

  const float* Ap = s1 + (size_t)b * L_ * F_ + (size_t)tr * 128 * F_;
  const float* Bp = s2 + (size_t)b * L_ * F_ + (size_t)tc * 128 * F_;

#pragma unroll 4
  for (int it = 0; it < 16; ++it) {
    int idx = it * 1024 + tid * 4;
    int r = idx >> 7, cc = idx & 127;
    float4 va = *(const float4*)(Ap + idx);
    float4 vb = *(const float4*)(Bp + idx);
    *(uint2*)&aL[r][cc] = make_uint2(pack2(va.x, va.y), pack2(va.z, va.w));
    *(uint2*)&bL[r][cc] = make_uint2(pack2(vb.x, vb.y), pack2(vb.z, vb.w));
  }
  if (tid < 128) q1[tid] = ws[OFF_N1 + (size_t)b * L_ + tr * 128 + tid];
  else           q2[tid - 128] = ws[OFF_N2 + (size_t)b * L_ + tc * 128 + (tid - 128)];
  __syncthreads();

  const int wave = tid >> 6, lane = tid & 63, quad = lane >> 4, l16 = lane & 15;
  const int m0 = (wave >> 1) * 64;  // r offset within tile
  const int n0 = (wave & 1) * 64;   // c offset within tile

  f32x4 acc[4][4] = {};
#pragma unroll
  for (int kc = 0; kc < 4; ++kc) {
    short8 af[4], bf[4];
#pragma unroll
    for (int mi = 0; mi < 4; ++mi)
      af[mi] = *(const short8*)&aL[m0 + mi * 16 + l16][kc * 32 + quad * 8];
#pragma unroll
    for (int nj = 0; nj < 4; ++nj)
      bf[nj] = *(const short8*)&bL[n0 + nj * 16 + l16][kc * 32 + quad * 8];
#pragma unroll
    for (int mi = 0; mi < 4; ++mi)
#pragma unroll
      for (int nj = 0; nj < 4; ++nj)
        acc[mi][nj] = __builtin_amdgcn_mfma_f32_16x16x32_bf16(af[mi], bf[nj], acc[mi][nj], 0, 0, 0);
  }

  // epilogue: row=quad*4+reg -> r (4 consecutive), col=lane&15 -> c: float4 stores
  float* Cb = ws + (size_t)b * SKEW_PB;
#pragma unroll
  for (int mi = 0; mi < 4; ++mi)
#pragma unroll
    for (int nj = 0; nj < 4; ++nj) {
      int lr0 = m0 + mi * 16 + quad * 4;
      int lc  = n0 + nj * 16 + l16;
      int r0  = tr * 128 + lr0;
      int c   = tc * 128 + lc;
      float4 v;
      v.x = sqrtf(fmaxf(q1[lr0 + 0] + q2[lc] - 2.0f * acc[mi][nj][0], 0.0f));
      v.y = sqrtf(fmaxf(q1[lr0 + 1] + q2[lc] - 2.0f * acc[mi][nj][1], 0.0f));
      v.z = sqrtf(fmaxf(q1[lr0 + 2] + q2[lc] - 2.0f * acc[mi][nj][2], 0.0f));
      v.w = sqrtf(fmaxf(q1[lr0 + 3] + q2[lc] - 2.0f * acc[mi][nj][3], 0.0f));
      *(float4*)&Cb[(size_t)(c + 2 * (r0 >> 4)) * 1024 + r0] = v;
    }
}

// one wave per batch; lane l owns rows 16l..16l+15 (0-based), stagger-2 pipeline.
__global__ __launch_bounds__(64, 1) void dtw_kernel(const float* __restrict__ ws,
                                                    float* __restrict__ out) {
  const int b = blockIdx.x, lane = threadIdx.x;
  const float* Cb = ws + (size_t)b * SKEW_PB + lane * 16;

  float4 buf[PF_][4];
#pragma unroll
  for (int s = 0; s < PF_; ++s)
#pragma unroll
    for (int k = 0; k < 4; ++k)
      buf[s][k] = *(const float4*)(Cb + (size_t)s * 1024 + k * 4);
  const float* pc = Cb + (size_t)PF_ * 1024;

  float left[16];
#pragma unroll
  for (int r = 0; r < 16; ++r) left[r] = BIGV;
  float bot = BIGV, shA = BIGV, shB = BIGV;
  const bool l0 = (lane == 0);
  int tm = -2 * lane;  // column index c at step t

#pragma unroll 8
  for (int t = 0; t < TSTEPS_; ++t) {
    float shN = __shfl_up(bot, 1, 64);  // carries lane-1 bot as of end of t-1

    // prefetch column t+PF (off-chain)
    float4 nb0 = *(const float4*)(pc + 0);
    float4 nb1 = *(const float4*)(pc + 4);
    float4 nb2 = *(const float4*)(pc + 8);
    float4 nb3 = *(const float4*)(pc + 12);
    pc += 1024;

    const float4* cb = buf[t & (PF_ - 1)];
    float cv[16] = { cb[0].x, cb[0].y, cb[0].z, cb[0].w,
                     cb[1].x, cb[1].y, cb[1].z, cb[1].w,
                     cb[2].x, cb[2].y, cb[2].z, cb[2].w,
                     cb[3].x, cb[3].y, cb[3].z, cb[3].w };

    // stagger-2: up = lane-1 bot @ col c (2 steps old), diag = @ col c-1 (3 steps old)
    float upT = l0 ? BIGV : shA;
    float dgT = l0 ? ((t == 0) ? 0.0f : BIGV) : shB;
    bool  act = ((unsigned)tm < 1024u);

    float cur = cv[0] + fminf(fminf(dgT, upT), left[0]);
    cur = act ? cur : BIGV;  // single mask keeps inactive lanes at "infinity"
    float nl[16];
    nl[0] = cur;
#pragma unroll
    for (int r = 1; r < 16; ++r) {
      cur = cv[r] + fminf(fminf(left[r - 1], left[r]), cur);
      nl[r] = cur;
    }
#pragma unroll
    for (int r = 0; r < 16; ++r) left[r] = nl[r];
    bot = nl[15];
    shB = shA; shA = shN;

    buf[t & (PF_ - 1)][0] = nb0;
    buf[t & (PF_ - 1)][1] = nb1;
    buf[t & (PF_ - 1)][2] = nb2;
    buf[t & (PF_ - 1)][3] = nb3;

    if (t == 1149) {  // lane 63 at c=1023: bot = D[1024][1024]
      if (lane == 63) out[b] = 1.0f / (1.0f + bot * (1.0f / 2048.0f));
    }
    tm += 1;
  }
}

extern "C" void kernel_launch(void* const* d_in, const int* in_sizes, int n_in,
                              void* d_out, int out_size, void* d_ws, size_t ws_size,
                              hipStream_t stream) {
  const float* s1 = (const float*)d_in[0];
  const float* s2 = (const float*)d_in[1];
  float* out = (float*)d_out;
  float* ws  = (float*)d_ws;

  norm_kernel<<<dim3((2 * B_ * L_) / 4), 256, 0, stream>>>(s1, s2, ws);
  cost_kernel<<<dim3(64, B_), 256, 0, stream>>>(s1, s2, ws);
  dtw_kernel<<<dim3(B_), 64, 0, stream>>>(ws, out);
}